// Round 1
// baseline (180.671 us; speedup 1.0000x reference)
//
#include <hip/hip_runtime.h>
#include <math.h>

namespace {

constexpr int N  = 4096;
constexpr int E  = 256;
constexpr int H  = 8;
constexpr int DH = 32;
constexpr int BS = 8;
constexpr float SCALE   = 0.17677669529663687f;  // 1/sqrt(32)
constexpr float NEG_BIG = -3.0e38f;

// ---------------------------------------------------------------------------
// QKV projection: out = A @ W^T + b, A = x+pe (Q,K) or x (V).
// M-tile 128, N-tile 64, K-chunk 16. 256 threads, 8x4 acc per thread.
// LDS tiles stored k-major (transposed) so compute reads are float4.
// Block (0,0,mat=2) also computes batch segment bounds via binary search.
// ---------------------------------------------------------------------------
__global__ __launch_bounds__(256) void qkv_kernel(
    const float* __restrict__ x, const float* __restrict__ pe,
    const int* __restrict__ xb,
    const float* __restrict__ Wq, const float* __restrict__ Wk,
    const float* __restrict__ Wv,
    const float* __restrict__ bq, const float* __restrict__ bk,
    const float* __restrict__ bv,
    float* __restrict__ qo, float* __restrict__ ko, float* __restrict__ vo,
    int* __restrict__ seg)
{
  const int mat = blockIdx.z;
  const float* __restrict__ W  = (mat == 0) ? Wq : (mat == 1 ? Wk : Wv);
  const float* __restrict__ bi = (mat == 0) ? bq : (mat == 1 ? bk : bv);
  float* __restrict__ out      = (mat == 0) ? qo : (mat == 1 ? ko : vo);
  const int m0 = blockIdx.x * 128;
  const int n0 = blockIdx.y * 64;
  const int t  = threadIdx.x;
  const int tx = t & 15, ty = t >> 4;

  if (mat == 2 && blockIdx.x == 0 && blockIdx.y == 0 && t <= BS) {
    // first index i with xb[i] >= t  (xb is sorted)
    int lo = 0, hi = N;
    while (lo < hi) { int mid = (lo + hi) >> 1; if (xb[mid] < t) lo = mid + 1; else hi = mid; }
    seg[t] = lo;
  }

  __shared__ float As[16 * 128];  // [k][m]
  __shared__ float Bs[16 * 64];   // [k][n]

  float acc[8][4];
#pragma unroll
  for (int i = 0; i < 8; ++i)
#pragma unroll
    for (int j = 0; j < 4; ++j) acc[i][j] = 0.f;

  const int ar = t >> 1;        // A row in tile 0..127
  const int af = (t & 1) * 2;   // which pair of float4s along k
  const int wr = t >> 2;        // W row (output col) in tile 0..63
  const int wf = t & 3;         // float4 along k
  const bool addpe = (mat < 2);

  const float* xrow = x  + (size_t)(m0 + ar) * E;
  const float* prow = pe + (size_t)(m0 + ar) * E;
  const float* wrow = W  + (size_t)(n0 + wr) * E;

  for (int kk = 0; kk < E; kk += 16) {
    float4 a0 = *(const float4*)(xrow + kk + af * 4);
    float4 a1 = *(const float4*)(xrow + kk + af * 4 + 4);
    if (addpe) {
      float4 p0 = *(const float4*)(prow + kk + af * 4);
      float4 p1 = *(const float4*)(prow + kk + af * 4 + 4);
      a0.x += p0.x; a0.y += p0.y; a0.z += p0.z; a0.w += p0.w;
      a1.x += p1.x; a1.y += p1.y; a1.z += p1.z; a1.w += p1.w;
    }
    float4 w0 = *(const float4*)(wrow + kk + wf * 4);
    __syncthreads();
    As[(af * 4 + 0) * 128 + ar] = a0.x;
    As[(af * 4 + 1) * 128 + ar] = a0.y;
    As[(af * 4 + 2) * 128 + ar] = a0.z;
    As[(af * 4 + 3) * 128 + ar] = a0.w;
    As[(af * 4 + 4) * 128 + ar] = a1.x;
    As[(af * 4 + 5) * 128 + ar] = a1.y;
    As[(af * 4 + 6) * 128 + ar] = a1.z;
    As[(af * 4 + 7) * 128 + ar] = a1.w;
    Bs[(wf * 4 + 0) * 64 + wr] = w0.x;
    Bs[(wf * 4 + 1) * 64 + wr] = w0.y;
    Bs[(wf * 4 + 2) * 64 + wr] = w0.z;
    Bs[(wf * 4 + 3) * 64 + wr] = w0.w;
    __syncthreads();
#pragma unroll
    for (int k = 0; k < 16; ++k) {
      float4 aA = *(const float4*)&As[k * 128 + ty * 8];
      float4 aB = *(const float4*)&As[k * 128 + ty * 8 + 4];
      float4 bV = *(const float4*)&Bs[k * 64 + tx * 4];
      const float av[8] = {aA.x, aA.y, aA.z, aA.w, aB.x, aB.y, aB.z, aB.w};
      const float bv4[4] = {bV.x, bV.y, bV.z, bV.w};
#pragma unroll
      for (int i = 0; i < 8; ++i)
#pragma unroll
        for (int j = 0; j < 4; ++j) acc[i][j] += av[i] * bv4[j];
    }
  }
  const float4 bb = *(const float4*)(bi + n0 + tx * 4);
#pragma unroll
  for (int i = 0; i < 8; ++i) {
    const int row = m0 + ty * 8 + i;
    float4 r;
    r.x = acc[i][0] + bb.x; r.y = acc[i][1] + bb.y;
    r.z = acc[i][2] + bb.z; r.w = acc[i][3] + bb.w;
    *(float4*)(out + (size_t)row * E + n0 + tx * 4) = r;
  }
}

// ---------------------------------------------------------------------------
// Flash attention over block-diagonal mask. Block = 64 query rows x 1 head.
// Q/K staged transposed [d][row] stride 64 (conflict-free float4 reads);
// V transposed stride 66 (float2 reads, <=2-way conflicts). P via LDS.
// Thread (tx,ty): rows ty*4+i, score cols tx*4+j, ctx dims tx*2+{0,1}.
// ---------------------------------------------------------------------------
__global__ __launch_bounds__(256) void attn_kernel(
    const float* __restrict__ qb, const float* __restrict__ kbuf,
    const float* __restrict__ vbuf, const int* __restrict__ xb,
    const int* __restrict__ seg, float* __restrict__ ctxb)
{
  const int i0 = blockIdx.x * 64;
  const int h  = blockIdx.y;
  const int t  = threadIdx.x;
  const int tx = t & 15, ty = t >> 4;

  __shared__ float Qt[32 * 64];
  __shared__ float Kt[32 * 64];
  __shared__ float Vt[32 * 66];
  __shared__ float Ps[64 * 64];
  __shared__ int   bt[64];

  {  // stage Q transposed
    const int r  = t >> 2;
    const int fb = (t & 3) * 2;
#pragma unroll
    for (int u = 0; u < 2; ++u) {
      const int f4 = fb + u;
      float4 qv = *(const float4*)(qb + (size_t)(i0 + r) * E + h * DH + f4 * 4);
      Qt[(f4 * 4 + 0) * 64 + r] = qv.x;
      Qt[(f4 * 4 + 1) * 64 + r] = qv.y;
      Qt[(f4 * 4 + 2) * 64 + r] = qv.z;
      Qt[(f4 * 4 + 3) * 64 + r] = qv.w;
    }
  }
  int rbatch[4];
#pragma unroll
  for (int i = 0; i < 4; ++i) rbatch[i] = xb[i0 + ty * 4 + i];
  const int kstart = seg[xb[i0]];
  const int kend   = seg[xb[i0 + 63] + 1];

  float m_[4], l_[4], ca[4][2];
#pragma unroll
  for (int i = 0; i < 4; ++i) { m_[i] = NEG_BIG; l_[i] = 0.f; ca[i][0] = 0.f; ca[i][1] = 0.f; }
  const int d0 = tx * 2;

  for (int j0 = kstart; j0 < kend; j0 += 64) {
    __syncthreads();  // previous PV finished reading LDS
    {
      const int r  = t >> 2;
      const int fb = (t & 3) * 2;
      const int j  = j0 + r;
      const bool val = (j < kend);
#pragma unroll
      for (int u = 0; u < 2; ++u) {
        const int f4 = fb + u;
        float4 kv = val ? *(const float4*)(kbuf + (size_t)j * E + h * DH + f4 * 4)
                        : make_float4(0.f, 0.f, 0.f, 0.f);
        float4 vv = val ? *(const float4*)(vbuf + (size_t)j * E + h * DH + f4 * 4)
                        : make_float4(0.f, 0.f, 0.f, 0.f);
        Kt[(f4 * 4 + 0) * 64 + r] = kv.x;
        Kt[(f4 * 4 + 1) * 64 + r] = kv.y;
        Kt[(f4 * 4 + 2) * 64 + r] = kv.z;
        Kt[(f4 * 4 + 3) * 64 + r] = kv.w;
        Vt[(f4 * 4 + 0) * 66 + r] = vv.x;
        Vt[(f4 * 4 + 1) * 66 + r] = vv.y;
        Vt[(f4 * 4 + 2) * 66 + r] = vv.z;
        Vt[(f4 * 4 + 3) * 66 + r] = vv.w;
      }
      if (t < 64) bt[t] = (j0 + t < kend) ? xb[j0 + t] : -1;
    }
    __syncthreads();

    // ---- scores: s[i][j] = q_i . k_j
    float s[4][4];
#pragma unroll
    for (int i = 0; i < 4; ++i)
#pragma unroll
      for (int j = 0; j < 4; ++j) s[i][j] = 0.f;
#pragma unroll 8
    for (int d = 0; d < 32; ++d) {
      float4 qv = *(const float4*)&Qt[d * 64 + ty * 4];
      float4 kv = *(const float4*)&Kt[d * 64 + tx * 4];
      const float qa[4] = {qv.x, qv.y, qv.z, qv.w};
      const float ka[4] = {kv.x, kv.y, kv.z, kv.w};
#pragma unroll
      for (int i = 0; i < 4; ++i)
#pragma unroll
        for (int j = 0; j < 4; ++j) s[i][j] += qa[i] * ka[j];
    }
    int kbb[4];
#pragma unroll
    for (int j = 0; j < 4; ++j) kbb[j] = bt[tx * 4 + j];

#pragma unroll
    for (int i = 0; i < 4; ++i) {
      float p[4];
      float sm = NEG_BIG;
#pragma unroll
      for (int j = 0; j < 4; ++j) {
        s[i][j] = (kbb[j] == rbatch[i]) ? s[i][j] * SCALE : NEG_BIG;
        sm = fmaxf(sm, s[i][j]);
      }
#pragma unroll
      for (int off = 1; off < 16; off <<= 1) sm = fmaxf(sm, __shfl_xor(sm, off, 64));
      const float mn = fmaxf(m_[i], sm);
      if (mn > -1.0e37f) {
        const float alpha = (m_[i] > -1.0e37f) ? __expf(m_[i] - mn) : 0.f;
        float ps = 0.f;
#pragma unroll
        for (int j = 0; j < 4; ++j) {
          p[j] = (s[i][j] > -1.0e37f) ? __expf(s[i][j] - mn) : 0.f;
          ps += p[j];
        }
        l_[i] = l_[i] * alpha + ps;
        ca[i][0] *= alpha; ca[i][1] *= alpha;
        m_[i] = mn;
      } else {
#pragma unroll
        for (int j = 0; j < 4; ++j) p[j] = 0.f;
      }
      *(float4*)&Ps[(ty * 4 + i) * 64 + tx * 4] = make_float4(p[0], p[1], p[2], p[3]);
    }
    __syncthreads();

    // ---- PV: ca[i][dd] += sum_j P[r][j] * V[j][d0+dd]
#pragma unroll 4
    for (int g = 0; g < 16; ++g) {
      float4 p0 = *(const float4*)&Ps[(ty * 4 + 0) * 64 + g * 4];
      float4 p1 = *(const float4*)&Ps[(ty * 4 + 1) * 64 + g * 4];
      float4 p2 = *(const float4*)&Ps[(ty * 4 + 2) * 64 + g * 4];
      float4 p3 = *(const float4*)&Ps[(ty * 4 + 3) * 64 + g * 4];
      float2 va0 = *(const float2*)&Vt[(d0 + 0) * 66 + g * 4];
      float2 va1 = *(const float2*)&Vt[(d0 + 0) * 66 + g * 4 + 2];
      float2 vb0 = *(const float2*)&Vt[(d0 + 1) * 66 + g * 4];
      float2 vb1 = *(const float2*)&Vt[(d0 + 1) * 66 + g * 4 + 2];
      ca[0][0] += p0.x * va0.x + p0.y * va0.y + p0.z * va1.x + p0.w * va1.y;
      ca[0][1] += p0.x * vb0.x + p0.y * vb0.y + p0.z * vb1.x + p0.w * vb1.y;
      ca[1][0] += p1.x * va0.x + p1.y * va0.y + p1.z * va1.x + p1.w * va1.y;
      ca[1][1] += p1.x * vb0.x + p1.y * vb0.y + p1.z * vb1.x + p1.w * vb1.y;
      ca[2][0] += p2.x * va0.x + p2.y * va0.y + p2.z * va1.x + p2.w * va1.y;
      ca[2][1] += p2.x * vb0.x + p2.y * vb0.y + p2.z * vb1.x + p2.w * vb1.y;
      ca[3][0] += p3.x * va0.x + p3.y * va0.y + p3.z * va1.x + p3.w * va1.y;
      ca[3][1] += p3.x * vb0.x + p3.y * vb0.y + p3.z * vb1.x + p3.w * vb1.y;
    }
  }

  // finalize: total l across the 16 tx lanes, then normalize + store
#pragma unroll
  for (int i = 0; i < 4; ++i) {
    float lt = l_[i];
#pragma unroll
    for (int off = 1; off < 16; off <<= 1) lt += __shfl_xor(lt, off, 64);
    const float inv = 1.0f / lt;
    float2 o;
    o.x = ca[i][0] * inv;
    o.y = ca[i][1] * inv;
    *(float2*)(ctxb + (size_t)(i0 + ty * 4 + i) * E + h * DH + d0) = o;
  }
}

// ---------------------------------------------------------------------------
// Output projection: y = ctx @ Wo^T + bo + x  (residual fused)
// ---------------------------------------------------------------------------
__global__ __launch_bounds__(256) void proj_kernel(
    const float* __restrict__ ctxb, const float* __restrict__ x,
    const float* __restrict__ Wo, const float* __restrict__ bo,
    float* __restrict__ yo)
{
  const int m0 = blockIdx.x * 128;
  const int n0 = blockIdx.y * 64;
  const int t  = threadIdx.x;
  const int tx = t & 15, ty = t >> 4;

  __shared__ float As[16 * 128];
  __shared__ float Bs[16 * 64];

  float acc[8][4];
#pragma unroll
  for (int i = 0; i < 8; ++i)
#pragma unroll
    for (int j = 0; j < 4; ++j) acc[i][j] = 0.f;

  const int ar = t >> 1;
  const int af = (t & 1) * 2;
  const int wr = t >> 2;
  const int wf = t & 3;

  const float* arow = ctxb + (size_t)(m0 + ar) * E;
  const float* wrow = Wo   + (size_t)(n0 + wr) * E;

  for (int kk = 0; kk < E; kk += 16) {
    float4 a0 = *(const float4*)(arow + kk + af * 4);
    float4 a1 = *(const float4*)(arow + kk + af * 4 + 4);
    float4 w0 = *(const float4*)(wrow + kk + wf * 4);
    __syncthreads();
    As[(af * 4 + 0) * 128 + ar] = a0.x;
    As[(af * 4 + 1) * 128 + ar] = a0.y;
    As[(af * 4 + 2) * 128 + ar] = a0.z;
    As[(af * 4 + 3) * 128 + ar] = a0.w;
    As[(af * 4 + 4) * 128 + ar] = a1.x;
    As[(af * 4 + 5) * 128 + ar] = a1.y;
    As[(af * 4 + 6) * 128 + ar] = a1.z;
    As[(af * 4 + 7) * 128 + ar] = a1.w;
    Bs[(wf * 4 + 0) * 64 + wr] = w0.x;
    Bs[(wf * 4 + 1) * 64 + wr] = w0.y;
    Bs[(wf * 4 + 2) * 64 + wr] = w0.z;
    Bs[(wf * 4 + 3) * 64 + wr] = w0.w;
    __syncthreads();
#pragma unroll
    for (int k = 0; k < 16; ++k) {
      float4 aA = *(const float4*)&As[k * 128 + ty * 8];
      float4 aB = *(const float4*)&As[k * 128 + ty * 8 + 4];
      float4 bV = *(const float4*)&Bs[k * 64 + tx * 4];
      const float av[8] = {aA.x, aA.y, aA.z, aA.w, aB.x, aB.y, aB.z, aB.w};
      const float bv4[4] = {bV.x, bV.y, bV.z, bV.w};
#pragma unroll
      for (int i = 0; i < 8; ++i)
#pragma unroll
        for (int j = 0; j < 4; ++j) acc[i][j] += av[i] * bv4[j];
    }
  }
  const float4 bb = *(const float4*)(bo + n0 + tx * 4);
#pragma unroll
  for (int i = 0; i < 8; ++i) {
    const int row = m0 + ty * 8 + i;
    const float4 xr = *(const float4*)(x + (size_t)row * E + n0 + tx * 4);
    float4 r;
    r.x = acc[i][0] + bb.x + xr.x;
    r.y = acc[i][1] + bb.y + xr.y;
    r.z = acc[i][2] + bb.z + xr.z;
    r.w = acc[i][3] + bb.w + xr.w;
    *(float4*)(yo + (size_t)row * E + n0 + tx * 4) = r;
  }
}

// ---------------------------------------------------------------------------
// Row LayerNorm: one wave per row (64 lanes x float4 = 256 cols)
// ---------------------------------------------------------------------------
__global__ __launch_bounds__(256) void ln_kernel(
    const float* __restrict__ yb, const float* __restrict__ gamma,
    const float* __restrict__ beta, float* __restrict__ out)
{
  const int row  = blockIdx.x * 4 + (threadIdx.x >> 6);
  const int lane = threadIdx.x & 63;
  const float4 yv = *(const float4*)(yb + (size_t)row * E + lane * 4);
  float s  = yv.x + yv.y + yv.z + yv.w;
  float s2 = yv.x * yv.x + yv.y * yv.y + yv.z * yv.z + yv.w * yv.w;
#pragma unroll
  for (int off = 1; off < 64; off <<= 1) {
    s  += __shfl_xor(s, off, 64);
    s2 += __shfl_xor(s2, off, 64);
  }
  const float mu  = s * (1.0f / E);
  const float var = s2 * (1.0f / E) - mu * mu;
  const float rs  = rsqrtf(var + 1e-5f);
  const float4 g = *(const float4*)(gamma + lane * 4);
  const float4 b = *(const float4*)(beta + lane * 4);
  float4 o;
  o.x = (yv.x - mu) * rs * g.x + b.x;
  o.y = (yv.y - mu) * rs * g.y + b.y;
  o.z = (yv.z - mu) * rs * g.z + b.z;
  o.w = (yv.w - mu) * rs * g.w + b.w;
  *(float4*)(out + (size_t)row * E + lane * 4) = o;
}

}  // namespace

extern "C" void kernel_launch(void* const* d_in, const int* in_sizes, int n_in,
                              void* d_out, int out_size, void* d_ws, size_t ws_size,
                              hipStream_t stream) {
  const float* x     = (const float*)d_in[0];
  const float* pe    = (const float*)d_in[1];
  const int*   xb    = (const int*)d_in[2];
  const float* Wq    = (const float*)d_in[3];
  const float* Wk    = (const float*)d_in[4];
  const float* Wv    = (const float*)d_in[5];
  const float* bq    = (const float*)d_in[6];
  const float* bk    = (const float*)d_in[7];
  const float* bv    = (const float*)d_in[8];
  const float* Wo    = (const float*)d_in[9];
  const float* bo    = (const float*)d_in[10];
  const float* gamma = (const float*)d_in[11];
  const float* beta  = (const float*)d_in[12];
  float* out = (float*)d_out;

  float* ws = (float*)d_ws;
  const size_t NE = (size_t)N * E;
  float* qb  = ws;
  float* kb  = ws + NE;
  float* vb  = ws + 2 * NE;
  float* cb  = ws + 3 * NE;
  float* yb  = ws + 4 * NE;
  int*   seg = (int*)(ws + 5 * NE);

  qkv_kernel<<<dim3(32, 4, 3), 256, 0, stream>>>(x, pe, xb, Wq, Wk, Wv,
                                                 bq, bk, bv, qb, kb, vb, seg);
  attn_kernel<<<dim3(64, 8), 256, 0, stream>>>(qb, kb, vb, xb, seg, cb);
  proj_kernel<<<dim3(32, 4), 256, 0, stream>>>(cb, x, Wo, bo, yb);
  ln_kernel<<<dim3(1024), 256, 0, stream>>>(yb, gamma, beta, out);
}

// Round 2
// 87.185 us; speedup vs baseline: 2.0723x; 2.0723x over previous
//
#include <hip/hip_runtime.h>
#include <math.h>

namespace {

constexpr int N  = 4096;
constexpr int E  = 256;
constexpr int H  = 8;
constexpr int DH = 32;
constexpr int BS = 8;
// fold 1/sqrt(DH) and log2(e) so softmax runs in exp2 domain
constexpr float CL = 0.17677669529663687f * 1.4426950408889634f;

typedef __bf16 bf16x8 __attribute__((ext_vector_type(8)));
typedef __bf16 bf16x4 __attribute__((ext_vector_type(4)));
typedef __bf16 bf16x2 __attribute__((ext_vector_type(2)));
typedef float  f32x4  __attribute__((ext_vector_type(4)));
typedef unsigned int uint4v __attribute__((ext_vector_type(4)));

#if __has_builtin(__builtin_amdgcn_exp2f)
#define EXP2F(x) __builtin_amdgcn_exp2f(x)
#else
#define EXP2F(x) __expf((x) * 0.6931471805599453f)
#endif

__device__ inline unsigned int pack_bf16x2(float a, float b) {
  bf16x2 t;
  t.x = (__bf16)a;
  t.y = (__bf16)b;
  return __builtin_bit_cast(unsigned int, t);
}

// ---------------------------------------------------------------------------
// QKV projection (f32 compute): out = A @ W^T + b, A = x+pe (Q,K) or x (V).
// Emits bf16: Q,K as [N][E]; V transposed as vt[E][N] (per-head [32][N] rows)
// so the attention kernel loads all MFMA fragments straight from global.
// Block (0,0,mat=2) also computes batch segment bounds via binary search.
// ---------------------------------------------------------------------------
__global__ __launch_bounds__(256) void qkv_kernel(
    const float* __restrict__ x, const float* __restrict__ pe,
    const int* __restrict__ xb,
    const float* __restrict__ Wq, const float* __restrict__ Wk,
    const float* __restrict__ Wv,
    const float* __restrict__ bq, const float* __restrict__ bk,
    const float* __restrict__ bv,
    __bf16* __restrict__ qo, __bf16* __restrict__ ko,
    __bf16* __restrict__ vt, int* __restrict__ seg)
{
  const int mat = blockIdx.z;
  const float* __restrict__ W  = (mat == 0) ? Wq : (mat == 1 ? Wk : Wv);
  const float* __restrict__ bi = (mat == 0) ? bq : (mat == 1 ? bk : bv);
  const int m0 = blockIdx.x * 128;
  const int n0 = blockIdx.y * 64;
  const int t  = threadIdx.x;
  const int tx = t & 15, ty = t >> 4;

  if (mat == 2 && blockIdx.x == 0 && blockIdx.y == 0 && t <= BS) {
    int lo = 0, hi = N;
    while (lo < hi) { int mid = (lo + hi) >> 1; if (xb[mid] < t) lo = mid + 1; else hi = mid; }
    seg[t] = lo;
  }

  __shared__ float As[16 * 128];  // [k][m]
  __shared__ float Bs[16 * 64];   // [k][n]

  float acc[8][4];
#pragma unroll
  for (int i = 0; i < 8; ++i)
#pragma unroll
    for (int j = 0; j < 4; ++j) acc[i][j] = 0.f;

  const int ar = t >> 1;
  const int af = (t & 1) * 2;
  const int wr = t >> 2;
  const int wf = t & 3;
  const bool addpe = (mat < 2);

  const float* xrow = x  + (size_t)(m0 + ar) * E;
  const float* prow = pe + (size_t)(m0 + ar) * E;
  const float* wrow = W  + (size_t)(n0 + wr) * E;

  for (int kk = 0; kk < E; kk += 16) {
    float4 a0 = *(const float4*)(xrow + kk + af * 4);
    float4 a1 = *(const float4*)(xrow + kk + af * 4 + 4);
    if (addpe) {
      float4 p0 = *(const float4*)(prow + kk + af * 4);
      float4 p1 = *(const float4*)(prow + kk + af * 4 + 4);
      a0.x += p0.x; a0.y += p0.y; a0.z += p0.z; a0.w += p0.w;
      a1.x += p1.x; a1.y += p1.y; a1.z += p1.z; a1.w += p1.w;
    }
    float4 w0 = *(const float4*)(wrow + kk + wf * 4);
    __syncthreads();
    As[(af * 4 + 0) * 128 + ar] = a0.x;
    As[(af * 4 + 1) * 128 + ar] = a0.y;
    As[(af * 4 + 2) * 128 + ar] = a0.z;
    As[(af * 4 + 3) * 128 + ar] = a0.w;
    As[(af * 4 + 4) * 128 + ar] = a1.x;
    As[(af * 4 + 5) * 128 + ar] = a1.y;
    As[(af * 4 + 6) * 128 + ar] = a1.z;
    As[(af * 4 + 7) * 128 + ar] = a1.w;
    Bs[(wf * 4 + 0) * 64 + wr] = w0.x;
    Bs[(wf * 4 + 1) * 64 + wr] = w0.y;
    Bs[(wf * 4 + 2) * 64 + wr] = w0.z;
    Bs[(wf * 4 + 3) * 64 + wr] = w0.w;
    __syncthreads();
#pragma unroll
    for (int k = 0; k < 16; ++k) {
      float4 aA = *(const float4*)&As[k * 128 + ty * 8];
      float4 aB = *(const float4*)&As[k * 128 + ty * 8 + 4];
      float4 bV = *(const float4*)&Bs[k * 64 + tx * 4];
      const float av[8] = {aA.x, aA.y, aA.z, aA.w, aB.x, aB.y, aB.z, aB.w};
      const float bv4[4] = {bV.x, bV.y, bV.z, bV.w};
#pragma unroll
      for (int i = 0; i < 8; ++i)
#pragma unroll
        for (int j = 0; j < 4; ++j) acc[i][j] += av[i] * bv4[j];
    }
  }
  const float4 bb = *(const float4*)(bi + n0 + tx * 4);
  const float bbj[4] = {bb.x, bb.y, bb.z, bb.w};
  if (mat < 2) {
    __bf16* outb = (mat == 0) ? qo : ko;
#pragma unroll
    for (int i = 0; i < 8; ++i) {
      const int row = m0 + ty * 8 + i;
      bf16x4 o;
      o.x = (__bf16)(acc[i][0] + bbj[0]);
      o.y = (__bf16)(acc[i][1] + bbj[1]);
      o.z = (__bf16)(acc[i][2] + bbj[2]);
      o.w = (__bf16)(acc[i][3] + bbj[3]);
      *reinterpret_cast<bf16x4*>(outb + (size_t)row * E + n0 + tx * 4) = o;
    }
  } else {
    // vt[e][n], pack 8 consecutive n (rows) per store
#pragma unroll
    for (int j = 0; j < 4; ++j) {
      bf16x8 o;
#pragma unroll
      for (int i = 0; i < 8; ++i) o[i] = (__bf16)(acc[i][j] + bbj[j]);
      *reinterpret_cast<bf16x8*>(vt + (size_t)(n0 + tx * 4 + j) * N + m0 + ty * 8) = o;
    }
  }
}

// ---------------------------------------------------------------------------
// MFMA flash attention, block-diagonal mask. No LDS, no barriers.
// Wave = 16 query rows x 1 head; block = 4 waves = 64 rows.
// Swapped QK: S^T = mfma(K, Q^T) -> lane holds 16 keys' scores for ONE row
//   (row = lane&15), masks/softmax are per-lane arithmetic + xor16/32 reduce.
// Swapped PV: ctx^T = mfma(V^T, P^T); P^T B-frags built via 16 shfl + packs.
// ---------------------------------------------------------------------------
__global__ __launch_bounds__(256) void attn_kernel(
    const __bf16* __restrict__ qb, const __bf16* __restrict__ kb,
    const __bf16* __restrict__ vt, const int* __restrict__ xb,
    const int* __restrict__ seg, float* __restrict__ ctxb)
{
  const int h    = blockIdx.y;
  const int wv   = threadIdx.x >> 6;
  const int lane = threadIdx.x & 63;
  const int l15  = lane & 15;
  const int g    = lane >> 4;
  const int hb   = (lane >> 5) & 1;
  const int qrow = blockIdx.x * 64 + wv * 16 + l15;

  const int b  = xb[qrow];
  const int lo = seg[b];
  const int hi = seg[b + 1];

  // Q^T B-fragment: b[i] = Q[qrow][h*32 + 8g + i]
  const bf16x8 qf = *reinterpret_cast<const bf16x8*>(
      qb + (size_t)qrow * E + h * DH + g * 8);

  const int kstart = __shfl(lo, 0, 64);
  const int kend   = __shfl(hi, 15, 64);

  f32x4 acc0 = {0.f, 0.f, 0.f, 0.f};   // ctx^T dims 0..15  (this lane: 4g+r)
  f32x4 acc1 = {0.f, 0.f, 0.f, 0.f};   // ctx^T dims 16..31
  float m_run = -1.0e30f, l_run = 0.f;

  for (int j0 = kstart & ~63; j0 < kend; j0 += 64) {
    // QK^T (swapped): s[mt] = K-tile(16 keys) . Q^T
    f32x4 s[4];
#pragma unroll
    for (int mt = 0; mt < 4; ++mt) {
      const bf16x8 kf = *reinterpret_cast<const bf16x8*>(
          kb + (size_t)(j0 + 16 * mt + l15) * E + h * DH + g * 8);
      const f32x4 z = {0.f, 0.f, 0.f, 0.f};
      s[mt] = __builtin_amdgcn_mfma_f32_16x16x32_bf16(kf, qf, z, 0, 0, 0);
    }
    // V^T A-fragments for this key tile (issue early)
    bf16x8 vf0[2], vf1[2];
#pragma unroll
    for (int ks = 0; ks < 2; ++ks) {
      vf0[ks] = *reinterpret_cast<const bf16x8*>(
          vt + (size_t)(h * DH + l15) * N + j0 + 32 * ks + 8 * g);
      vf1[ks] = *reinterpret_cast<const bf16x8*>(
          vt + (size_t)(h * DH + 16 + l15) * N + j0 + 32 * ks + 8 * g);
    }

    // online softmax over this tile's 64 keys for row l15
    float p[4][4];
    float tm = -1.0e30f;
#pragma unroll
    for (int mt = 0; mt < 4; ++mt)
#pragma unroll
      for (int r = 0; r < 4; ++r) {
        const int key = j0 + 16 * mt + 4 * g + r;
        float sc = s[mt][r] * CL;
        sc = (key >= lo && key < hi) ? sc : -1.0e30f;
        p[mt][r] = sc;
        tm = fmaxf(tm, sc);
      }
    tm = fmaxf(tm, __shfl_xor(tm, 16, 64));
    tm = fmaxf(tm, __shfl_xor(tm, 32, 64));
    const float mn    = fmaxf(m_run, tm);
    const float alpha = EXP2F(m_run - mn);
    float ts = 0.f;
#pragma unroll
    for (int mt = 0; mt < 4; ++mt)
#pragma unroll
      for (int r = 0; r < 4; ++r) {
        const float sc = p[mt][r];
        const float e  = (sc > -1.0e29f) ? EXP2F(sc - mn) : 0.f;
        p[mt][r] = e;
        ts += e;
      }
    ts += __shfl_xor(ts, 16, 64);
    ts += __shfl_xor(ts, 32, 64);
    m_run = mn;
    l_run = l_run * alpha + ts;
#pragma unroll
    for (int r = 0; r < 4; ++r) { acc0[r] *= alpha; acc1[r] *= alpha; }

    // pack P to bf16 pairs: pk[mt][c] = (p[mt][2c], p[mt][2c+1])
    unsigned int pk[4][2];
#pragma unroll
    for (int mt = 0; mt < 4; ++mt) {
      pk[mt][0] = pack_bf16x2(p[mt][0], p[mt][1]);
      pk[mt][1] = pack_bf16x2(p[mt][2], p[mt][3]);
    }
    // PV (swapped): acc += V^T . P^T ; build P^T B-frag via cross-lane shfl
#pragma unroll
    for (int ks = 0; ks < 2; ++ks) {
      unsigned int bwa[4];
#pragma unroll
      for (int w4 = 0; w4 < 4; ++w4) {
        const int gs  = (2 * g + (w4 >> 1)) & 3;
        const int src = (gs << 4) | l15;
        const unsigned int v0 = __shfl(pk[2 * ks][w4 & 1], src, 64);
        const unsigned int v1 = __shfl(pk[2 * ks + 1][w4 & 1], src, 64);
        bwa[w4] = hb ? v1 : v0;
      }
      uint4v bw = {bwa[0], bwa[1], bwa[2], bwa[3]};
      const bf16x8 pf = __builtin_bit_cast(bf16x8, bw);
      acc0 = __builtin_amdgcn_mfma_f32_16x16x32_bf16(vf0[ks], pf, acc0, 0, 0, 0);
      acc1 = __builtin_amdgcn_mfma_f32_16x16x32_bf16(vf1[ks], pf, acc1, 0, 0, 0);
    }
  }

  // epilogue: ctx[qrow][h*32 + dim], dims 4g+r (+16)
  const float inv = 1.0f / l_run;
  float4 o0, o1;
  o0.x = acc0[0] * inv; o0.y = acc0[1] * inv; o0.z = acc0[2] * inv; o0.w = acc0[3] * inv;
  o1.x = acc1[0] * inv; o1.y = acc1[1] * inv; o1.z = acc1[2] * inv; o1.w = acc1[3] * inv;
  float* orow = ctxb + (size_t)qrow * E + h * DH;
  *(float4*)(orow + 4 * g)      = o0;
  *(float4*)(orow + 16 + 4 * g) = o1;
}

// ---------------------------------------------------------------------------
// Output projection: y = ctx @ Wo^T + bo + x  (residual fused, f32)
// ---------------------------------------------------------------------------
__global__ __launch_bounds__(256) void proj_kernel(
    const float* __restrict__ ctxb, const float* __restrict__ x,
    const float* __restrict__ Wo, const float* __restrict__ bo,
    float* __restrict__ yo)
{
  const int m0 = blockIdx.x * 128;
  const int n0 = blockIdx.y * 64;
  const int t  = threadIdx.x;
  const int tx = t & 15, ty = t >> 4;

  __shared__ float As[16 * 128];
  __shared__ float Bs[16 * 64];

  float acc[8][4];
#pragma unroll
  for (int i = 0; i < 8; ++i)
#pragma unroll
    for (int j = 0; j < 4; ++j) acc[i][j] = 0.f;

  const int ar = t >> 1;
  const int af = (t & 1) * 2;
  const int wr = t >> 2;
  const int wf = t & 3;

  const float* arow = ctxb + (size_t)(m0 + ar) * E;
  const float* wrow = Wo   + (size_t)(n0 + wr) * E;

  for (int kk = 0; kk < E; kk += 16) {
    float4 a0 = *(const float4*)(arow + kk + af * 4);
    float4 a1 = *(const float4*)(arow + kk + af * 4 + 4);
    float4 w0 = *(const float4*)(wrow + kk + wf * 4);
    __syncthreads();
    As[(af * 4 + 0) * 128 + ar] = a0.x;
    As[(af * 4 + 1) * 128 + ar] = a0.y;
    As[(af * 4 + 2) * 128 + ar] = a0.z;
    As[(af * 4 + 3) * 128 + ar] = a0.w;
    As[(af * 4 + 4) * 128 + ar] = a1.x;
    As[(af * 4 + 5) * 128 + ar] = a1.y;
    As[(af * 4 + 6) * 128 + ar] = a1.z;
    As[(af * 4 + 7) * 128 + ar] = a1.w;
    Bs[(wf * 4 + 0) * 64 + wr] = w0.x;
    Bs[(wf * 4 + 1) * 64 + wr] = w0.y;
    Bs[(wf * 4 + 2) * 64 + wr] = w0.z;
    Bs[(wf * 4 + 3) * 64 + wr] = w0.w;
    __syncthreads();
#pragma unroll
    for (int k = 0; k < 16; ++k) {
      float4 aA = *(const float4*)&As[k * 128 + ty * 8];
      float4 aB = *(const float4*)&As[k * 128 + ty * 8 + 4];
      float4 bV = *(const float4*)&Bs[k * 64 + tx * 4];
      const float av[8] = {aA.x, aA.y, aA.z, aA.w, aB.x, aB.y, aB.z, aB.w};
      const float bv4[4] = {bV.x, bV.y, bV.z, bV.w};
#pragma unroll
      for (int i = 0; i < 8; ++i)
#pragma unroll
        for (int j = 0; j < 4; ++j) acc[i][j] += av[i] * bv4[j];
    }
  }
  const float4 bb = *(const float4*)(bo + n0 + tx * 4);
#pragma unroll
  for (int i = 0; i < 8; ++i) {
    const int row = m0 + ty * 8 + i;
    const float4 xr = *(const float4*)(x + (size_t)row * E + n0 + tx * 4);
    float4 r;
    r.x = acc[i][0] + bb.x + xr.x;
    r.y = acc[i][1] + bb.y + xr.y;
    r.z = acc[i][2] + bb.z + xr.z;
    r.w = acc[i][3] + bb.w + xr.w;
    *(float4*)(yo + (size_t)row * E + n0 + tx * 4) = r;
  }
}

// ---------------------------------------------------------------------------
// Row LayerNorm: one wave per row
// ---------------------------------------------------------------------------
__global__ __launch_bounds__(256) void ln_kernel(
    const float* __restrict__ yb, const float* __restrict__ gamma,
    const float* __restrict__ beta, float* __restrict__ out)
{
  const int row  = blockIdx.x * 4 + (threadIdx.x >> 6);
  const int lane = threadIdx.x & 63;
  const float4 yv = *(const float4*)(yb + (size_t)row * E + lane * 4);
  float s  = yv.x + yv.y + yv.z + yv.w;
  float s2 = yv.x * yv.x + yv.y * yv.y + yv.z * yv.z + yv.w * yv.w;
#pragma unroll
  for (int off = 1; off < 64; off <<= 1) {
    s  += __shfl_xor(s, off, 64);
    s2 += __shfl_xor(s2, off, 64);
  }
  const float mu  = s * (1.0f / E);
  const float var = s2 * (1.0f / E) - mu * mu;
  const float rs  = rsqrtf(var + 1e-5f);
  const float4 g = *(const float4*)(gamma + lane * 4);
  const float4 b = *(const float4*)(beta + lane * 4);
  float4 o;
  o.x = (yv.x - mu) * rs * g.x + b.x;
  o.y = (yv.y - mu) * rs * g.y + b.y;
  o.z = (yv.z - mu) * rs * g.z + b.z;
  o.w = (yv.w - mu) * rs * g.w + b.w;
  *(float4*)(out + (size_t)row * E + lane * 4) = o;
}

}  // namespace

extern "C" void kernel_launch(void* const* d_in, const int* in_sizes, int n_in,
                              void* d_out, int out_size, void* d_ws, size_t ws_size,
                              hipStream_t stream) {
  const float* x     = (const float*)d_in[0];
  const float* pe    = (const float*)d_in[1];
  const int*   xb    = (const int*)d_in[2];
  const float* Wq    = (const float*)d_in[3];
  const float* Wk    = (const float*)d_in[4];
  const float* Wv    = (const float*)d_in[5];
  const float* bq    = (const float*)d_in[6];
  const float* bk    = (const float*)d_in[7];
  const float* bv    = (const float*)d_in[8];
  const float* Wo    = (const float*)d_in[9];
  const float* bo    = (const float*)d_in[10];
  const float* gamma = (const float*)d_in[11];
  const float* beta  = (const float*)d_in[12];
  float* out = (float*)d_out;

  char* wsb = (char*)d_ws;
  const size_t NE = (size_t)N * E;
  __bf16* qb16 = (__bf16*)(wsb);                 // 2 MB
  __bf16* kb16 = (__bf16*)(wsb + 2 * NE);        // 2 MB
  __bf16* vt16 = (__bf16*)(wsb + 4 * NE);        // 2 MB  [E][N]
  float*  cb   = (float*)(wsb + 6 * NE);         // 4 MB
  float*  yb   = (float*)(wsb + 6 * NE + 4 * NE);// 4 MB
  int*    seg  = (int*)(wsb + 6 * NE + 8 * NE);

  qkv_kernel<<<dim3(32, 4, 3), 256, 0, stream>>>(x, pe, xb, Wq, Wk, Wv,
                                                 bq, bk, bv, qb16, kb16, vt16, seg);
  attn_kernel<<<dim3(64, 8), 256, 0, stream>>>(qb16, kb16, vt16, xb, seg, cb);
  proj_kernel<<<dim3(32, 4), 256, 0, stream>>>(cb, x, Wo, bo, yb);
  ln_kernel<<<dim3(1024), 256, 0, stream>>>(yb, gamma, beta, out);
}